// Round 1
// baseline (76686.005 us; speedup 1.0000x reference)
//
#include <hip/hip_runtime.h>

// ---------------------------------------------------------------------------
// MPNODE_STL10 forward pass, fp32 baseline.
// Structure: stem conv -> IN+relu -> ode1 -> 1x1 -> IN+relu -> pool -> ode2
//            -> 1x1 -> IN+relu -> pool -> ode3 -> GAP -> head.
// ode_rhs = conv3x3+b+relu -> instnorm(no affine) -> conv3x3 (transposed,
// flipped weights) -> negate.  RK4 stage updates fused into conv2 epilogue.
// ---------------------------------------------------------------------------

#define TS  16   // spatial tile (TS x TS outputs per block)
#define OCT 16   // output channels per block
#define CIT 8    // input channels per LDS chunk

// ---------------- conv3x3 + bias (+optional relu) --------------------------
__global__ __launch_bounds__(256) void conv3x3_kernel(
    const float* __restrict__ in, const float* __restrict__ w,
    const float* __restrict__ bias, float* __restrict__ out,
    int N, int Cin, int Cout, int H, int W, int tilesX, int relu)
{
    __shared__ float sIn[CIT][TS + 2][TS + 2];
    __shared__ float sW[OCT][CIT][9];
    const int tid = threadIdx.x;
    const int tx = tid & (TS - 1), ty = tid >> 4;
    const int tileX = blockIdx.x % tilesX, tileY = blockIdx.x / tilesX;
    const int x0 = tileX * TS, y0 = tileY * TS;
    const int oc0 = blockIdx.y * OCT;
    const int n = blockIdx.z;
    const int HW = H * W;

    float acc[OCT];
#pragma unroll
    for (int o = 0; o < OCT; o++) acc[o] = 0.f;

    for (int ic0 = 0; ic0 < Cin; ic0 += CIT) {
        // stage input tile (TS+2)^2 x CIT
        for (int idx = tid; idx < CIT * (TS + 2) * (TS + 2); idx += 256) {
            int c  = idx / ((TS + 2) * (TS + 2));
            int r  = idx % ((TS + 2) * (TS + 2));
            int iy = r / (TS + 2), ix = r % (TS + 2);
            int gy = y0 + iy - 1, gx = x0 + ix - 1;
            int ic = ic0 + c;
            float v = 0.f;
            if (ic < Cin && gy >= 0 && gy < H && gx >= 0 && gx < W)
                v = in[(size_t)(n * Cin + ic) * HW + gy * W + gx];
            sIn[c][iy][ix] = v;
        }
        // stage weights OCT x CIT x 9 (OIHW)
        for (int idx = tid; idx < OCT * CIT * 9; idx += 256) {
            int o = idx / (CIT * 9);
            int r = idx % (CIT * 9);
            int c = r / 9, k = r % 9;
            int oc = oc0 + o, ic = ic0 + c;
            sW[o][c][k] = (oc < Cout && ic < Cin)
                              ? w[((size_t)oc * Cin + ic) * 9 + k] : 0.f;
        }
        __syncthreads();
#pragma unroll
        for (int c = 0; c < CIT; c++)
#pragma unroll
            for (int kh = 0; kh < 3; kh++)
#pragma unroll
                for (int kw = 0; kw < 3; kw++) {
                    float v = sIn[c][ty + kh][tx + kw];
#pragma unroll
                    for (int o = 0; o < OCT; o++)
                        acc[o] = fmaf(v, sW[o][c][kh * 3 + kw], acc[o]);
                }
        __syncthreads();
    }

    int gy = y0 + ty, gx = x0 + tx;
    if (gy < H && gx < W) {
#pragma unroll
        for (int o = 0; o < OCT; o++) {
            int oc = oc0 + o;
            if (oc < Cout) {
                float v = acc[o] + bias[oc];
                if (relu) v = fmaxf(v, 0.f);
                out[(size_t)(n * Cout + oc) * HW + gy * W + gx] = v;
            }
        }
    }
}

// ------- conv3x3 with transposed+flipped weights, normalized input, --------
// ------- negate, and fused RK4 stage epilogue ------------------------------
// mode 0: acc = k;       ydst = ybase + acoef*k
// mode 1: acc += 2k;     ydst = ybase + acoef*k
// mode 3: ydst = ybase + dt6*(acc + k)
__global__ __launch_bounds__(256) void conv3x3t_rk4_kernel(
    const float* __restrict__ zin, const float* __restrict__ w,
    const float* __restrict__ mu, const float* __restrict__ rstd,
    const float* __restrict__ ybase, float* __restrict__ accb,
    float* __restrict__ ydst,
    int C, int H, int W, int tilesX, int mode, float acoef, float dt6)
{
    __shared__ float sIn[CIT][TS + 2][TS + 2];
    __shared__ float sW[OCT][CIT][9];
    const int tid = threadIdx.x;
    const int tx = tid & (TS - 1), ty = tid >> 4;
    const int tileX = blockIdx.x % tilesX, tileY = blockIdx.x / tilesX;
    const int x0 = tileX * TS, y0 = tileY * TS;
    const int oc0 = blockIdx.y * OCT;
    const int n = blockIdx.z;
    const int HW = H * W;

    float acc[OCT];
#pragma unroll
    for (int o = 0; o < OCT; o++) acc[o] = 0.f;

    for (int ic0 = 0; ic0 < C; ic0 += CIT) {
        for (int idx = tid; idx < CIT * (TS + 2) * (TS + 2); idx += 256) {
            int c  = idx / ((TS + 2) * (TS + 2));
            int r  = idx % ((TS + 2) * (TS + 2));
            int iy = r / (TS + 2), ix = r % (TS + 2);
            int gy = y0 + iy - 1, gx = x0 + ix - 1;
            int ic = ic0 + c;
            float v = 0.f;
            if (gy >= 0 && gy < H && gx >= 0 && gx < W) {
                int nc = n * C + ic;
                v = (zin[(size_t)nc * HW + gy * W + gx] - mu[nc]) * rstd[nc];
            }
            sIn[c][iy][ix] = v;
        }
        // Wt[oc][ic][kh][kw] = W[ic][oc][2-kh][2-kw]
        for (int idx = tid; idx < OCT * CIT * 9; idx += 256) {
            int o = idx / (CIT * 9);
            int r = idx % (CIT * 9);
            int c = r / 9, k = r % 9;
            int kh = k / 3, kw = k % 3;
            int oc = oc0 + o, ic = ic0 + c;
            sW[o][c][k] = w[((size_t)ic * C + oc) * 9 + (2 - kh) * 3 + (2 - kw)];
        }
        __syncthreads();
#pragma unroll
        for (int c = 0; c < CIT; c++)
#pragma unroll
            for (int kh = 0; kh < 3; kh++)
#pragma unroll
                for (int kw = 0; kw < 3; kw++) {
                    float v = sIn[c][ty + kh][tx + kw];
#pragma unroll
                    for (int o = 0; o < OCT; o++)
                        acc[o] = fmaf(v, sW[o][c][kh * 3 + kw], acc[o]);
                }
        __syncthreads();
    }

    int gy = y0 + ty, gx = x0 + tx;
    if (gy < H && gx < W) {
#pragma unroll
        for (int o = 0; o < OCT; o++) {
            int oc = oc0 + o;
            size_t idx = (size_t)(n * C + oc) * HW + gy * W + gx;
            float k = -acc[o];
            if (mode == 0) {
                accb[idx] = k;
                ydst[idx] = ybase[idx] + acoef * k;
            } else if (mode == 3) {
                ydst[idx] = ybase[idx] + dt6 * (accb[idx] + k);
            } else {
                accb[idx] += 2.f * k;
                ydst[idx] = ybase[idx] + acoef * k;
            }
        }
    }
}

// ---------------- instance-norm stats (per n,c over HW) --------------------
__global__ __launch_bounds__(256) void stats_kernel(
    const float* __restrict__ x, float* __restrict__ mu, float* __restrict__ rstd,
    int HW, float inv_hw)
{
    int nc = blockIdx.x;
    const float* p = x + (size_t)nc * HW;
    float s = 0.f, ss = 0.f;
    for (int i = threadIdx.x; i < HW; i += 256) {
        float v = p[i];
        s += v;
        ss = fmaf(v, v, ss);
    }
    for (int off = 32; off; off >>= 1) {
        s  += __shfl_down(s, off, 64);
        ss += __shfl_down(ss, off, 64);
    }
    __shared__ float aS[4], aSS[4];
    int wid = threadIdx.x >> 6, lane = threadIdx.x & 63;
    if (lane == 0) { aS[wid] = s; aSS[wid] = ss; }
    __syncthreads();
    if (threadIdx.x == 0) {
        s  = aS[0] + aS[1] + aS[2] + aS[3];
        ss = aSS[0] + aSS[1] + aSS[2] + aSS[3];
        float m = s * inv_hw;
        float var = fmaf(-m, m, ss * inv_hw);
        mu[nc] = m;
        rstd[nc] = rsqrtf(var + 1e-5f);
    }
}

// ---------------- (x-mu)*rstd*g + b, relu ----------------------------------
__global__ __launch_bounds__(256) void norm_affine_relu_kernel(
    const float* __restrict__ in, float* __restrict__ out,
    const float* __restrict__ mu, const float* __restrict__ rstd,
    const float* __restrict__ g, const float* __restrict__ b,
    int C, int HW, size_t total)
{
    size_t i = (size_t)blockIdx.x * 256 + threadIdx.x;
    if (i >= total) return;
    size_t nc = i / HW;
    int c = (int)(nc % C);
    float v = (in[i] - mu[nc]) * rstd[nc] * g[c] + b[c];
    out[i] = fmaxf(v, 0.f);
}

// ---------------- 2x2 average pool -----------------------------------------
__global__ __launch_bounds__(256) void avgpool2_kernel(
    const float* __restrict__ in, float* __restrict__ out,
    int Ho, int Wo, size_t total)
{
    size_t i = (size_t)blockIdx.x * 256 + threadIdx.x;
    if (i >= total) return;
    int wo = (int)(i % Wo);
    int ho = (int)((i / Wo) % Ho);
    size_t nc = i / ((size_t)Wo * Ho);
    const float* p = in + nc * (size_t)(4 * Ho * Wo) + (size_t)(2 * ho) * (2 * Wo) + 2 * wo;
    out[i] = 0.25f * (p[0] + p[1] + p[2 * Wo] + p[2 * Wo + 1]);
}

// ---------------- 1x1 conv + bias ------------------------------------------
#define C1OCT 8
__global__ __launch_bounds__(256) void conv1x1_kernel(
    const float* __restrict__ in, const float* __restrict__ w,
    const float* __restrict__ bias, float* __restrict__ out,
    int Cin, int Cout, int HW)
{
    int p = blockIdx.x * 256 + threadIdx.x;
    int oc0 = blockIdx.y * C1OCT;
    int n = blockIdx.z;
    if (p >= HW) return;
    float acc[C1OCT];
#pragma unroll
    for (int o = 0; o < C1OCT; o++) acc[o] = 0.f;
    const float* ip = in + (size_t)n * Cin * HW + p;
    for (int ic = 0; ic < Cin; ic++) {
        float v = ip[(size_t)ic * HW];
#pragma unroll
        for (int o = 0; o < C1OCT; o++)
            acc[o] = fmaf(v, w[(size_t)(oc0 + o) * Cin + ic], acc[o]);
    }
    float* op = out + ((size_t)n * Cout + oc0) * HW + p;
#pragma unroll
    for (int o = 0; o < C1OCT; o++) op[(size_t)o * HW] = acc[o] + bias[oc0 + o];
}

// ---------------- head: out[n,k] = sum_c mean[n,c]*hw[k,c] + hb[k] ---------
__global__ __launch_bounds__(128) void head_kernel(
    const float* __restrict__ m, const float* __restrict__ hw,
    const float* __restrict__ hb, float* __restrict__ out, int C)
{
    int t = threadIdx.x;
    if (t < 80) {
        int n = t / 10, k = t % 10;
        float acc = hb[k];
        for (int c = 0; c < C; c++)
            acc = fmaf(m[n * C + c], hw[k * C + c], acc);
        out[t] = acc;
    }
}

// ---------------------------------------------------------------------------
// host orchestration
// ---------------------------------------------------------------------------
static void run_rhs(const float* yin, const float* W, const float* b,
                    float* z, float* mu, float* rs,
                    const float* ybase, float* accb, float* ydst,
                    int mode, float acoef, int C, int H, hipStream_t s)
{
    int tiles = (H + TS - 1) / TS;
    int HW = H * H;
    dim3 grid(tiles * tiles, C / OCT, 8);
    conv3x3_kernel<<<grid, 256, 0, s>>>(yin, W, b, z, 8, C, C, H, H, tiles, 1);
    stats_kernel<<<8 * C, 256, 0, s>>>(z, mu, rs, HW, 1.f / HW);
    conv3x3t_rk4_kernel<<<grid, 256, 0, s>>>(z, W, mu, rs, ybase, accb, ydst,
                                             C, H, H, tiles, mode, acoef, 0.25f / 6.f);
}

static void ode_block(float* y, float* t, float* z, float* a,
                      float* mu, float* rs,
                      const float* Wbank, const float* bbank,
                      int C, int H, hipStream_t s)
{
    const float dt = 0.25f;
    for (int i = 0; i < 4; i++) {
        int j = (i + 1 > 3) ? 3 : i + 1;
        const float* W1 = Wbank + (size_t)i * C * C * 9;
        const float* b1 = bbank + (size_t)i * C;
        const float* W4 = Wbank + (size_t)j * C * C * 9;
        const float* b4 = bbank + (size_t)j * C;
        run_rhs(y, W1, b1, z, mu, rs, y, a, t, 0, 0.5f * dt, C, H, s); // k1
        run_rhs(t, W1, b1, z, mu, rs, y, a, t, 1, 0.5f * dt, C, H, s); // k2
        run_rhs(t, W1, b1, z, mu, rs, y, a, t, 1, dt,        C, H, s); // k3
        run_rhs(t, W4, b4, z, mu, rs, y, a, y, 3, 0.f,       C, H, s); // k4+update
    }
}

extern "C" void kernel_launch(void* const* d_in, const int* in_sizes, int n_in,
                              void* d_out, int out_size, void* d_ws, size_t ws_size,
                              hipStream_t stream)
{
    const float* x       = (const float*)d_in[0];
    const float* stem_w  = (const float*)d_in[1];
    const float* stem_b  = (const float*)d_in[2];
    const float* norm1_g = (const float*)d_in[3];
    const float* norm1_b = (const float*)d_in[4];
    const float* ode1_W  = (const float*)d_in[5];
    const float* ode1_b  = (const float*)d_in[6];
    const float* conn1_w = (const float*)d_in[7];
    const float* conn1_b = (const float*)d_in[8];
    const float* norm3_g = (const float*)d_in[9];
    const float* norm3_b = (const float*)d_in[10];
    const float* ode2_W  = (const float*)d_in[11];
    const float* ode2_b  = (const float*)d_in[12];
    const float* conn2_w = (const float*)d_in[13];
    const float* conn2_b = (const float*)d_in[14];
    const float* norm4_g = (const float*)d_in[15];
    const float* norm4_b = (const float*)d_in[16];
    const float* ode3_W  = (const float*)d_in[17];
    const float* ode3_b  = (const float*)d_in[18];
    const float* head_w  = (const float*)d_in[19];
    const float* head_b  = (const float*)d_in[20];
    float* out = (float*)d_out;

    float* ws = (float*)d_ws;
    const size_t BUF = 4718592; // 8*64*96*96 (largest per-stage tensor)
    float* y  = ws;
    float* t  = ws + BUF;
    float* z  = ws + 2 * BUF;
    float* a  = ws + 3 * BUF;
    float* mu = ws + 4 * BUF;
    float* rs = mu + 2048;

    // ---- stem: conv3x3(3->64) + b -> IN(affine) -> relu ----
    {
        int H = 96, tiles = 6;
        dim3 grid(tiles * tiles, 64 / OCT, 8);
        conv3x3_kernel<<<grid, 256, 0, stream>>>(x, stem_w, stem_b, z,
                                                 8, 3, 64, H, H, tiles, 0);
        stats_kernel<<<8 * 64, 256, 0, stream>>>(z, mu, rs, H * H, 1.f / (H * H));
        size_t total = (size_t)8 * 64 * H * H;
        norm_affine_relu_kernel<<<(total + 255) / 256, 256, 0, stream>>>(
            z, y, mu, rs, norm1_g, norm1_b, 64, H * H, total);
    }

    // ---- ode1: C=64, 96x96 ----
    ode_block(y, t, z, a, mu, rs, ode1_W, ode1_b, 64, 96, stream);

    // ---- conn1: 1x1(64->128) -> IN(affine)+relu -> pool ----
    {
        int H = 96, HW = H * H, Cin = 64, Cout = 128;
        dim3 grid((HW + 255) / 256, Cout / C1OCT, 8);
        conv1x1_kernel<<<grid, 256, 0, stream>>>(y, conn1_w, conn1_b, t, Cin, Cout, HW);
        stats_kernel<<<8 * Cout, 256, 0, stream>>>(t, mu, rs, HW, 1.f / HW);
        size_t total = (size_t)8 * Cout * HW;
        norm_affine_relu_kernel<<<(total + 255) / 256, 256, 0, stream>>>(
            t, t, mu, rs, norm3_g, norm3_b, Cout, HW, total);
        size_t ptotal = (size_t)8 * Cout * 48 * 48;
        avgpool2_kernel<<<(ptotal + 255) / 256, 256, 0, stream>>>(t, y, 48, 48, ptotal);
    }

    // ---- ode2: C=128, 48x48 ----
    ode_block(y, t, z, a, mu, rs, ode2_W, ode2_b, 128, 48, stream);

    // ---- conn2: 1x1(128->256) -> IN(affine)+relu -> pool ----
    {
        int H = 48, HW = H * H, Cin = 128, Cout = 256;
        dim3 grid((HW + 255) / 256, Cout / C1OCT, 8);
        conv1x1_kernel<<<grid, 256, 0, stream>>>(y, conn2_w, conn2_b, t, Cin, Cout, HW);
        stats_kernel<<<8 * Cout, 256, 0, stream>>>(t, mu, rs, HW, 1.f / HW);
        size_t total = (size_t)8 * Cout * HW;
        norm_affine_relu_kernel<<<(total + 255) / 256, 256, 0, stream>>>(
            t, t, mu, rs, norm4_g, norm4_b, Cout, HW, total);
        size_t ptotal = (size_t)8 * Cout * 24 * 24;
        avgpool2_kernel<<<(ptotal + 255) / 256, 256, 0, stream>>>(t, y, 24, 24, ptotal);
    }

    // ---- ode3: C=256, 24x24 ----
    ode_block(y, t, z, a, mu, rs, ode3_W, ode3_b, 256, 24, stream);

    // ---- head: GAP + linear ----
    {
        int H = 24, HW = H * H, C = 256;
        stats_kernel<<<8 * C, 256, 0, stream>>>(y, mu, rs, HW, 1.f / HW);
        head_kernel<<<1, 128, 0, stream>>>(mu, head_w, head_b, out, C);
    }
}

// Round 2
// 9045.742 us; speedup vs baseline: 8.4776x; 8.4776x over previous
//
#include <hip/hip_runtime.h>

// ---------------------------------------------------------------------------
// MPNODE_STL10 forward, round 2: ODE convs as split-bf16 MFMA implicit GEMM.
//
// GEMM mapping per conv:  M = out-channels, N = pixels (8x x 4y per MFMA
// n-tile), K = (kh,kw) x in-channels (16-ic chunks per v_mfma_32x32x16_bf16).
// fp32 emulated as ah+al / bh+bl, 3 MFMAs per product-term (err ~1e-5).
// Weights pre-packed per ODE stage into A-fragment layout (hi/lo planes,
// dir0 = conv, dir1 = transposed+flipped conv).  Activations staged per
// ic-chunk into LDS as hi/lo bf16; instnorm fused into conv2 staging; RK4
// stage update fused into conv2 epilogue.
// ---------------------------------------------------------------------------

typedef __attribute__((ext_vector_type(8)))  short  s16x8;
typedef __attribute__((ext_vector_type(16))) float  f32x16;

__device__ __forceinline__ unsigned short bf16_rtne(float f) {
    unsigned u = __builtin_bit_cast(unsigned, f);
    unsigned r = u + 0x7FFFu + ((u >> 16) & 1u);
    return (unsigned short)(r >> 16);
}

// ---------------- weight pack: A-fragment layout ---------------------------
// plane layout (elems): [bank(4)][kp(9)][icc(C/16)][mt(C/32)][lane(64)][j(8)]
// hi plane then lo plane (PLANE = 36*C*C elems each); dir0 then dir1.
// A element (m = lane&31 -> oc, k = (lane>>5)*8+j -> ic within chunk).
__global__ __launch_bounds__(256) void pack_weights(
    const float* __restrict__ Wb, unsigned short* __restrict__ out, int C)
{
    const int dir = blockIdx.y;
    const size_t PLANE = (size_t)36 * C * C;
    size_t t = (size_t)blockIdx.x * 256 + threadIdx.x;
    if (t >= PLANE) return;
    int j = t & 7;
    int l = (t >> 3) & 63;
    size_t r = t >> 9;
    const int MT = C >> 5, ICC = C >> 4;
    int mt  = r % MT;  r /= MT;
    int icc = r % ICC; r /= ICC;
    int kp  = r % 9;
    int bank = r / 9;
    int oc = mt * 32 + (l & 31);
    int ic = icc * 16 + (l >> 5) * 8 + j;
    int kh = kp / 3, kw = kp % 3;
    float v;
    if (dir == 0)
        v = Wb[(((size_t)(bank * C + oc) * C + ic) * 3 + kh) * 3 + kw];
    else
        v = Wb[(((size_t)(bank * C + ic) * C + oc) * 3 + (2 - kh)) * 3 + (2 - kw)];
    unsigned short h = bf16_rtne(v);
    float hf = __builtin_bit_cast(float, (unsigned)h << 16);
    unsigned short lo = bf16_rtne(v - hf);
    unsigned short* base = out + (size_t)dir * 2 * PLANE;
    base[t] = h;
    base[PLANE + t] = lo;
}

// ---------------- MFMA conv kernel -----------------------------------------
// NW waves/block; wave n-tile = 32 px (8x x 4y); WX waves along x.
// Block: M = 64 oc (2 m-tiles per wave, all waves same M), N = NW*32 px.
// CONV2: input normalized by (mu,rstd); epilogue = negate + RK4 mode.
// !CONV2: epilogue = +bias, relu; ydst = z.
template<int NW, int WX, bool CONV2>
__global__ __launch_bounds__(NW * 64) void conv_mfma(
    const float* __restrict__ in,
    const unsigned short* __restrict__ pAhi,
    const unsigned short* __restrict__ pAlo,
    const float* __restrict__ bias,
    const float* __restrict__ mu, const float* __restrict__ rstd,
    const float* __restrict__ ybase, float* __restrict__ accb,
    float* __restrict__ ydst,
    int C, int H, int W, int tilesX, int mode, float acoef, float dt6)
{
    constexpr int TPX = 8 * WX;
    constexpr int TPY = 4 * (NW / WX);
    constexpr int HX = TPX + 2, HY = TPY + 2;
    __shared__ __align__(16) unsigned short sBh[HY * HX * 16];
    __shared__ __align__(16) unsigned short sBl[HY * HX * 16];

    const int tid = threadIdx.x;
    const int w = tid >> 6, lane = tid & 63;
    const int tileX = blockIdx.x % tilesX, tileY = blockIdx.x / tilesX;
    const int px0 = tileX * TPX, py0 = tileY * TPY;
    const int n = blockIdx.z;
    const int ocb = blockIdx.y * 64;
    const int HW = H * W;
    const int ICC = C >> 4, MT = C >> 5;
    const int offx = (w % WX) * 8, offy = (w / WX) * 4;
    const int xl = (lane & 7) + offx, yl = ((lane >> 3) & 3) + offy;
    const int half = lane >> 5;
    const int mtg0 = ocb >> 5;

    f32x16 acc[2] = {};

    for (int icc = 0; icc < ICC; icc++) {
        // ---- stage 16 input channels (hi/lo bf16) into LDS ----
        for (int e = tid; e < HY * HX * 16; e += NW * 64) {
            int ic = e / (HY * HX);
            int r  = e % (HY * HX);
            int y = r / HX, x = r % HX;
            int gy = py0 + y - 1, gx = px0 + x - 1;
            float v = 0.f;
            if (gy >= 0 && gy < H && gx >= 0 && gx < W) {
                int nc = n * C + icc * 16 + ic;
                v = in[(size_t)nc * HW + gy * W + gx];
                if (CONV2) v = (v - mu[nc]) * rstd[nc];
            }
            unsigned short h = bf16_rtne(v);
            float hf = __builtin_bit_cast(float, (unsigned)h << 16);
            unsigned short lo = bf16_rtne(v - hf);
            sBh[r * 16 + ic] = h;
            sBl[r * 16 + ic] = lo;
        }
        __syncthreads();
#pragma unroll
        for (int kp = 0; kp < 9; kp++) {
            const int kh = kp / 3, kw = kp % 3;
            int px = (yl + kh) * HX + (xl + kw);
            s16x8 bh = *(const s16x8*)&sBh[px * 16 + half * 8];
            s16x8 bl = *(const s16x8*)&sBl[px * 16 + half * 8];
            size_t ao = (((size_t)kp * ICC + icc) * MT + mtg0) * 512 + lane * 8;
            s16x8 ah0 = *(const s16x8*)&pAhi[ao];
            s16x8 al0 = *(const s16x8*)&pAlo[ao];
            s16x8 ah1 = *(const s16x8*)&pAhi[ao + 512];
            s16x8 al1 = *(const s16x8*)&pAlo[ao + 512];
            acc[0] = __builtin_amdgcn_mfma_f32_32x32x16_bf16(ah0, bh, acc[0], 0, 0, 0);
            acc[0] = __builtin_amdgcn_mfma_f32_32x32x16_bf16(al0, bh, acc[0], 0, 0, 0);
            acc[0] = __builtin_amdgcn_mfma_f32_32x32x16_bf16(ah0, bl, acc[0], 0, 0, 0);
            acc[1] = __builtin_amdgcn_mfma_f32_32x32x16_bf16(ah1, bh, acc[1], 0, 0, 0);
            acc[1] = __builtin_amdgcn_mfma_f32_32x32x16_bf16(al1, bh, acc[1], 0, 0, 0);
            acc[1] = __builtin_amdgcn_mfma_f32_32x32x16_bf16(ah1, bl, acc[1], 0, 0, 0);
        }
        __syncthreads();
    }

    // ---- epilogue: C/D layout col=lane&31, row=(reg&3)+8*(reg>>2)+4*(lane>>5)
    const int col = lane & 31;
    const int gx = px0 + (col & 7) + offx;
    const int gy = py0 + (col >> 3) + offy;
#pragma unroll
    for (int mt = 0; mt < 2; mt++) {
#pragma unroll
        for (int r = 0; r < 16; r++) {
            int row = (r & 3) + 8 * (r >> 2) + 4 * half;
            int oc = ocb + mt * 32 + row;
            size_t idx = (size_t)(n * C + oc) * HW + (size_t)gy * W + gx;
            float v = acc[mt][r];
            if (!CONV2) {
                v += bias[oc];
                ydst[idx] = fmaxf(v, 0.f);
            } else {
                float k = -v;
                if (mode == 0)      { accb[idx] = k;              ydst[idx] = ybase[idx] + acoef * k; }
                else if (mode == 3) { ydst[idx] = ybase[idx] + dt6 * (accb[idx] + k); }
                else                { accb[idx] += 2.f * k;       ydst[idx] = ybase[idx] + acoef * k; }
            }
        }
    }
}

// ---------------- fp32 stem conv (Cin=3), unchanged ------------------------
#define TS  16
#define OCT 16
#define CIT 8
__global__ __launch_bounds__(256) void conv3x3_kernel(
    const float* __restrict__ in, const float* __restrict__ w,
    const float* __restrict__ bias, float* __restrict__ out,
    int N, int Cin, int Cout, int H, int W, int tilesX, int relu)
{
    __shared__ float sIn[CIT][TS + 2][TS + 2];
    __shared__ float sW[OCT][CIT][9];
    const int tid = threadIdx.x;
    const int tx = tid & (TS - 1), ty = tid >> 4;
    const int tileX = blockIdx.x % tilesX, tileY = blockIdx.x / tilesX;
    const int x0 = tileX * TS, y0 = tileY * TS;
    const int oc0 = blockIdx.y * OCT;
    const int n = blockIdx.z;
    const int HW = H * W;

    float acc[OCT];
#pragma unroll
    for (int o = 0; o < OCT; o++) acc[o] = 0.f;

    for (int ic0 = 0; ic0 < Cin; ic0 += CIT) {
        for (int idx = tid; idx < CIT * (TS + 2) * (TS + 2); idx += 256) {
            int c  = idx / ((TS + 2) * (TS + 2));
            int r  = idx % ((TS + 2) * (TS + 2));
            int iy = r / (TS + 2), ix = r % (TS + 2);
            int gy = y0 + iy - 1, gx = x0 + ix - 1;
            int ic = ic0 + c;
            float v = 0.f;
            if (ic < Cin && gy >= 0 && gy < H && gx >= 0 && gx < W)
                v = in[(size_t)(n * Cin + ic) * HW + gy * W + gx];
            sIn[c][iy][ix] = v;
        }
        for (int idx = tid; idx < OCT * CIT * 9; idx += 256) {
            int o = idx / (CIT * 9);
            int r = idx % (CIT * 9);
            int c = r / 9, k = r % 9;
            int oc = oc0 + o, ic = ic0 + c;
            sW[o][c][k] = (oc < Cout && ic < Cin)
                              ? w[((size_t)oc * Cin + ic) * 9 + k] : 0.f;
        }
        __syncthreads();
#pragma unroll
        for (int c = 0; c < CIT; c++)
#pragma unroll
            for (int kh = 0; kh < 3; kh++)
#pragma unroll
                for (int kw = 0; kw < 3; kw++) {
                    float v = sIn[c][ty + kh][tx + kw];
#pragma unroll
                    for (int o = 0; o < OCT; o++)
                        acc[o] = fmaf(v, sW[o][c][kh * 3 + kw], acc[o]);
                }
        __syncthreads();
    }

    int gy = y0 + ty, gx = x0 + tx;
    if (gy < H && gx < W) {
#pragma unroll
        for (int o = 0; o < OCT; o++) {
            int oc = oc0 + o;
            if (oc < Cout) {
                float v = acc[o] + bias[oc];
                if (relu) v = fmaxf(v, 0.f);
                out[(size_t)(n * Cout + oc) * HW + gy * W + gx] = v;
            }
        }
    }
}

// ---------------- instance-norm stats --------------------------------------
__global__ __launch_bounds__(256) void stats_kernel(
    const float* __restrict__ x, float* __restrict__ mu, float* __restrict__ rstd,
    int HW, float inv_hw)
{
    int nc = blockIdx.x;
    const float* p = x + (size_t)nc * HW;
    float s = 0.f, ss = 0.f;
    for (int i = threadIdx.x; i < HW; i += 256) {
        float v = p[i];
        s += v;
        ss = fmaf(v, v, ss);
    }
    for (int off = 32; off; off >>= 1) {
        s  += __shfl_down(s, off, 64);
        ss += __shfl_down(ss, off, 64);
    }
    __shared__ float aS[4], aSS[4];
    int wid = threadIdx.x >> 6, lane = threadIdx.x & 63;
    if (lane == 0) { aS[wid] = s; aSS[wid] = ss; }
    __syncthreads();
    if (threadIdx.x == 0) {
        s  = aS[0] + aS[1] + aS[2] + aS[3];
        ss = aSS[0] + aSS[1] + aSS[2] + aSS[3];
        float m = s * inv_hw;
        float var = fmaf(-m, m, ss * inv_hw);
        mu[nc] = m;
        rstd[nc] = rsqrtf(var + 1e-5f);
    }
}

__global__ __launch_bounds__(256) void norm_affine_relu_kernel(
    const float* __restrict__ in, float* __restrict__ out,
    const float* __restrict__ mu, const float* __restrict__ rstd,
    const float* __restrict__ g, const float* __restrict__ b,
    int C, int HW, size_t total)
{
    size_t i = (size_t)blockIdx.x * 256 + threadIdx.x;
    if (i >= total) return;
    size_t nc = i / HW;
    int c = (int)(nc % C);
    float v = (in[i] - mu[nc]) * rstd[nc] * g[c] + b[c];
    out[i] = fmaxf(v, 0.f);
}

__global__ __launch_bounds__(256) void avgpool2_kernel(
    const float* __restrict__ in, float* __restrict__ out,
    int Ho, int Wo, size_t total)
{
    size_t i = (size_t)blockIdx.x * 256 + threadIdx.x;
    if (i >= total) return;
    int wo = (int)(i % Wo);
    int ho = (int)((i / Wo) % Ho);
    size_t nc = i / ((size_t)Wo * Ho);
    const float* p = in + nc * (size_t)(4 * Ho * Wo) + (size_t)(2 * ho) * (2 * Wo) + 2 * wo;
    out[i] = 0.25f * (p[0] + p[1] + p[2 * Wo] + p[2 * Wo + 1]);
}

#define C1OCT 8
__global__ __launch_bounds__(256) void conv1x1_kernel(
    const float* __restrict__ in, const float* __restrict__ w,
    const float* __restrict__ bias, float* __restrict__ out,
    int Cin, int Cout, int HW)
{
    int p = blockIdx.x * 256 + threadIdx.x;
    int oc0 = blockIdx.y * C1OCT;
    int n = blockIdx.z;
    if (p >= HW) return;
    float acc[C1OCT];
#pragma unroll
    for (int o = 0; o < C1OCT; o++) acc[o] = 0.f;
    const float* ip = in + (size_t)n * Cin * HW + p;
    for (int ic = 0; ic < Cin; ic++) {
        float v = ip[(size_t)ic * HW];
#pragma unroll
        for (int o = 0; o < C1OCT; o++)
            acc[o] = fmaf(v, w[(size_t)(oc0 + o) * Cin + ic], acc[o]);
    }
    float* op = out + ((size_t)n * Cout + oc0) * HW + p;
#pragma unroll
    for (int o = 0; o < C1OCT; o++) op[(size_t)o * HW] = acc[o] + bias[oc0 + o];
}

__global__ __launch_bounds__(128) void head_kernel(
    const float* __restrict__ m, const float* __restrict__ hw,
    const float* __restrict__ hb, float* __restrict__ out, int C)
{
    int t = threadIdx.x;
    if (t < 80) {
        int n = t / 10, k = t % 10;
        float acc = hb[k];
        for (int c = 0; c < C; c++)
            acc = fmaf(m[n * C + c], hw[k * C + c], acc);
        out[t] = acc;
    }
}

// ---------------------------------------------------------------------------
// host orchestration
// ---------------------------------------------------------------------------
struct OdeCfg { int C, H, tilesX, gridX, gridY, blockThreads; };
static const OdeCfg CFG[3] = {
    {64, 96, 6, 72, 1, 256},
    {128, 48, 3, 18, 2, 256},
    {256, 24, 3, 9, 4, 128},
};

static void launch_conv1(int st, const float* in, const unsigned short* pw,
                         const float* bias, float* z, hipStream_t s)
{
    const OdeCfg& c = CFG[st];
    if (st == 0)
        conv_mfma<4, 2, false><<<dim3(c.gridX, c.gridY, 8), 256, 0, s>>>(
            in, pw, pw + (size_t)36 * c.C * c.C, bias, nullptr, nullptr,
            nullptr, nullptr, z, c.C, c.H, c.H, c.tilesX, 0, 0.f, 0.f);
    else if (st == 1)
        conv_mfma<4, 2, false><<<dim3(c.gridX, c.gridY, 8), 256, 0, s>>>(
            in, pw, pw + (size_t)36 * c.C * c.C, bias, nullptr, nullptr,
            nullptr, nullptr, z, c.C, c.H, c.H, c.tilesX, 0, 0.f, 0.f);
    else
        conv_mfma<2, 1, false><<<dim3(c.gridX, c.gridY, 8), 128, 0, s>>>(
            in, pw, pw + (size_t)36 * c.C * c.C, bias, nullptr, nullptr,
            nullptr, nullptr, z, c.C, c.H, c.H, c.tilesX, 0, 0.f, 0.f);
}

static void launch_conv2(int st, const float* z, const unsigned short* pw,
                         const float* mu, const float* rs,
                         const float* ybase, float* accb, float* ydst,
                         int mode, float acoef, hipStream_t s)
{
    const OdeCfg& c = CFG[st];
    const float dt6 = 0.25f / 6.f;
    if (st == 0)
        conv_mfma<4, 2, true><<<dim3(c.gridX, c.gridY, 8), 256, 0, s>>>(
            z, pw, pw + (size_t)36 * c.C * c.C, nullptr, mu, rs,
            ybase, accb, ydst, c.C, c.H, c.H, c.tilesX, mode, acoef, dt6);
    else if (st == 1)
        conv_mfma<4, 2, true><<<dim3(c.gridX, c.gridY, 8), 256, 0, s>>>(
            z, pw, pw + (size_t)36 * c.C * c.C, nullptr, mu, rs,
            ybase, accb, ydst, c.C, c.H, c.H, c.tilesX, mode, acoef, dt6);
    else
        conv_mfma<2, 1, true><<<dim3(c.gridX, c.gridY, 8), 128, 0, s>>>(
            z, pw, pw + (size_t)36 * c.C * c.C, nullptr, mu, rs,
            ybase, accb, ydst, c.C, c.H, c.H, c.tilesX, mode, acoef, dt6);
}

static void ode_block_mfma(int st, float* y, float* t, float* z, float* a,
                           float* mu, float* rs, unsigned short* pack,
                           const float* bbank, hipStream_t s)
{
    const OdeCfg& c = CFG[st];
    const int C = c.C, HW = c.H * c.H;
    const size_t PLANE = (size_t)36 * C * C;
    const size_t BANK = (size_t)9 * C * C;
    const float dt = 0.25f;
    for (int i = 0; i < 4; i++) {
        int j = (i + 1 > 3) ? 3 : i + 1;
        const unsigned short* p1 = pack + i * BANK;              // dir0, bank i
        const unsigned short* p1t = pack + 2 * PLANE + i * BANK; // dir1, bank i
        const unsigned short* p4t = pack + 2 * PLANE + j * BANK; // dir1, bank j
        const unsigned short* p4 = pack + j * BANK;
        const float* b1 = bbank + (size_t)i * C;
        const float* b4 = bbank + (size_t)j * C;
        // k1
        launch_conv1(st, y, p1, b1, z, s);
        stats_kernel<<<8 * C, 256, 0, s>>>(z, mu, rs, HW, 1.f / HW);
        launch_conv2(st, z, p1t, mu, rs, y, a, t, 0, 0.5f * dt, s);
        // k2
        launch_conv1(st, t, p1, b1, z, s);
        stats_kernel<<<8 * C, 256, 0, s>>>(z, mu, rs, HW, 1.f / HW);
        launch_conv2(st, z, p1t, mu, rs, y, a, t, 1, 0.5f * dt, s);
        // k3
        launch_conv1(st, t, p1, b1, z, s);
        stats_kernel<<<8 * C, 256, 0, s>>>(z, mu, rs, HW, 1.f / HW);
        launch_conv2(st, z, p1t, mu, rs, y, a, t, 1, dt, s);
        // k4 + update
        launch_conv1(st, t, p4, b4, z, s);
        stats_kernel<<<8 * C, 256, 0, s>>>(z, mu, rs, HW, 1.f / HW);
        launch_conv2(st, z, p4t, mu, rs, y, a, y, 3, 0.f, s);
    }
}

extern "C" void kernel_launch(void* const* d_in, const int* in_sizes, int n_in,
                              void* d_out, int out_size, void* d_ws, size_t ws_size,
                              hipStream_t stream)
{
    const float* x       = (const float*)d_in[0];
    const float* stem_w  = (const float*)d_in[1];
    const float* stem_b  = (const float*)d_in[2];
    const float* norm1_g = (const float*)d_in[3];
    const float* norm1_b = (const float*)d_in[4];
    const float* ode1_W  = (const float*)d_in[5];
    const float* ode1_b  = (const float*)d_in[6];
    const float* conn1_w = (const float*)d_in[7];
    const float* conn1_b = (const float*)d_in[8];
    const float* norm3_g = (const float*)d_in[9];
    const float* norm3_b = (const float*)d_in[10];
    const float* ode2_W  = (const float*)d_in[11];
    const float* ode2_b  = (const float*)d_in[12];
    const float* conn2_w = (const float*)d_in[13];
    const float* conn2_b = (const float*)d_in[14];
    const float* norm4_g = (const float*)d_in[15];
    const float* norm4_b = (const float*)d_in[16];
    const float* ode3_W  = (const float*)d_in[17];
    const float* ode3_b  = (const float*)d_in[18];
    const float* head_w  = (const float*)d_in[19];
    const float* head_b  = (const float*)d_in[20];
    float* out = (float*)d_out;

    float* ws = (float*)d_ws;
    const size_t BUF = 4718592; // 8*64*96*96
    float* y  = ws;
    float* t  = ws + BUF;
    float* z  = ws + 2 * BUF;
    float* a  = ws + 3 * BUF;
    float* mu = ws + 4 * BUF;
    float* rs = mu + 2048;
    unsigned short* pack = (unsigned short*)(ws + 4 * BUF + 4096);

    // ---- stem: conv3x3(3->64)+b -> IN(affine) -> relu ----
    {
        int H = 96, tiles = 6;
        dim3 grid(tiles * tiles, 64 / OCT, 8);
        conv3x3_kernel<<<grid, 256, 0, stream>>>(x, stem_w, stem_b, z,
                                                 8, 3, 64, H, H, tiles, 0);
        stats_kernel<<<8 * 64, 256, 0, stream>>>(z, mu, rs, H * H, 1.f / (H * H));
        size_t total = (size_t)8 * 64 * H * H;
        norm_affine_relu_kernel<<<(total + 255) / 256, 256, 0, stream>>>(
            z, y, mu, rs, norm1_g, norm1_b, 64, H * H, total);
    }

    // ---- ode1 ----
    {
        size_t PLANE = (size_t)36 * 64 * 64;
        pack_weights<<<dim3((PLANE + 255) / 256, 2), 256, 0, stream>>>(ode1_W, pack, 64);
        ode_block_mfma(0, y, t, z, a, mu, rs, pack, ode1_b, stream);
    }

    // ---- conn1: 1x1(64->128) -> IN+relu -> pool ----
    {
        int H = 96, HW = H * H, Cin = 64, Cout = 128;
        dim3 grid((HW + 255) / 256, Cout / C1OCT, 8);
        conv1x1_kernel<<<grid, 256, 0, stream>>>(y, conn1_w, conn1_b, t, Cin, Cout, HW);
        stats_kernel<<<8 * Cout, 256, 0, stream>>>(t, mu, rs, HW, 1.f / HW);
        size_t total = (size_t)8 * Cout * HW;
        norm_affine_relu_kernel<<<(total + 255) / 256, 256, 0, stream>>>(
            t, t, mu, rs, norm3_g, norm3_b, Cout, HW, total);
        size_t ptotal = (size_t)8 * Cout * 48 * 48;
        avgpool2_kernel<<<(ptotal + 255) / 256, 256, 0, stream>>>(t, y, 48, 48, ptotal);
    }

    // ---- ode2 ----
    {
        size_t PLANE = (size_t)36 * 128 * 128;
        pack_weights<<<dim3((PLANE + 255) / 256, 2), 256, 0, stream>>>(ode2_W, pack, 128);
        ode_block_mfma(1, y, t, z, a, mu, rs, pack, ode2_b, stream);
    }

    // ---- conn2: 1x1(128->256) -> IN+relu -> pool ----
    {
        int H = 48, HW = H * H, Cin = 128, Cout = 256;
        dim3 grid((HW + 255) / 256, Cout / C1OCT, 8);
        conv1x1_kernel<<<grid, 256, 0, stream>>>(y, conn2_w, conn2_b, t, Cin, Cout, HW);
        stats_kernel<<<8 * Cout, 256, 0, stream>>>(t, mu, rs, HW, 1.f / HW);
        size_t total = (size_t)8 * Cout * HW;
        norm_affine_relu_kernel<<<(total + 255) / 256, 256, 0, stream>>>(
            t, t, mu, rs, norm4_g, norm4_b, Cout, HW, total);
        size_t ptotal = (size_t)8 * Cout * 24 * 24;
        avgpool2_kernel<<<(ptotal + 255) / 256, 256, 0, stream>>>(t, y, 24, 24, ptotal);
    }

    // ---- ode3 ----
    {
        size_t PLANE = (size_t)36 * 256 * 256;
        pack_weights<<<dim3((PLANE + 255) / 256, 2), 256, 0, stream>>>(ode3_W, pack, 256);
        ode_block_mfma(2, y, t, z, a, mu, rs, pack, ode3_b, stream);
    }

    // ---- head: GAP + linear ----
    {
        int H = 24, HW = H * H, C = 256;
        stats_kernel<<<8 * C, 256, 0, stream>>>(y, mu, rs, HW, 1.f / HW);
        head_kernel<<<1, 128, 0, stream>>>(mu, head_w, head_b, out, C);
    }
}

// Round 3
// 8086.018 us; speedup vs baseline: 9.4838x; 1.1187x over previous
//
#include <hip/hip_runtime.h>

// ---------------------------------------------------------------------------
// MPNODE_STL10 forward, round 3: latency-optimized split-bf16 MFMA conv.
//  - 1 m-tile (32 oc) per wave, gridY = C/32  -> 2-4x more waves in flight
//  - A (global) / B (LDS) fragments prefetched one kp ahead
//  - LDS B double-buffered over ic-chunks; staging loads into regs before the
//    MFMA loop, LDS writes after it (no ds_write in the ds_read/MFMA window)
//  - 3 independent accumulators (no dependent MFMA chain)
//  - B row stride 24 shorts (48B) -> bank-conflict-free fragment reads
//  - instnorm stats fused into conv1 epilogue (atomics, ping-pong sum bufs);
//    mu/rstd computed inline in conv2 staging. No standalone stats in odes.
// ---------------------------------------------------------------------------

typedef __attribute__((ext_vector_type(8)))  short  s16x8;
typedef __attribute__((ext_vector_type(16))) float  f32x16;

__device__ __forceinline__ unsigned short bf16_rtne(float f) {
    unsigned u = __builtin_bit_cast(unsigned, f);
    unsigned r = u + 0x7FFFu + ((u >> 16) & 1u);
    return (unsigned short)(r >> 16);
}

// ---------------- weight pack: A-fragment layout (unchanged) ---------------
// plane elems: [bank(4)][kp(9)][icc(C/16)][mt(C/32)][lane(64)][j(8)]
// hi plane then lo plane (PLANE = 36*C*C each); dir0 then dir1.
__global__ __launch_bounds__(256) void pack_weights(
    const float* __restrict__ Wb, unsigned short* __restrict__ out, int C)
{
    const int dir = blockIdx.y;
    const size_t PLANE = (size_t)36 * C * C;
    size_t t = (size_t)blockIdx.x * 256 + threadIdx.x;
    if (t >= PLANE) return;
    int j = t & 7;
    int l = (t >> 3) & 63;
    size_t r = t >> 9;
    const int MT = C >> 5, ICC = C >> 4;
    int mt  = r % MT;  r /= MT;
    int icc = r % ICC; r /= ICC;
    int kp  = r % 9;
    int bank = r / 9;
    int oc = mt * 32 + (l & 31);
    int ic = icc * 16 + (l >> 5) * 8 + j;
    int kh = kp / 3, kw = kp % 3;
    float v;
    if (dir == 0)
        v = Wb[(((size_t)(bank * C + oc) * C + ic) * 3 + kh) * 3 + kw];
    else
        v = Wb[(((size_t)(bank * C + ic) * C + oc) * 3 + (2 - kh)) * 3 + (2 - kw)];
    unsigned short h = bf16_rtne(v);
    float hf = __builtin_bit_cast(float, (unsigned)h << 16);
    unsigned short lo = bf16_rtne(v - hf);
    unsigned short* base = out + (size_t)dir * 2 * PLANE;
    base[t] = h;
    base[PLANE + t] = lo;
}

// ---------------- MFMA conv kernel -----------------------------------------
template<int NW, int WX, bool CONV2>
__global__ __launch_bounds__(NW * 64) void conv_mfma2(
    const float* __restrict__ in,
    const unsigned short* __restrict__ pAhi,
    const unsigned short* __restrict__ pAlo,
    const float* __restrict__ bias,
    const float* __restrict__ sums_in,   // conv2: [s | ss], 2*NCtot floats
    float* __restrict__ sums_out,        // conv1: accumulate; conv2: zero tgt
    const float* __restrict__ ybase, float* __restrict__ accb,
    float* __restrict__ ydst,
    int C, int H, int W, int tilesX, int NCtot, float inv_hw,
    int mode, float acoef, float dt6)
{
    constexpr int TPX = 8 * WX, TPY = 4 * (NW / WX);
    constexpr int HX = TPX + 2, HY = TPY + 2;
    constexpr int NROW = HX * HY;
    constexpr int RS = 24;               // row stride (shorts), 48B
    constexpr int PL = NROW * RS;        // plane (shorts)
    constexpr int BUFS = 2 * PL;         // hi+lo
    constexpr int NTHR = NW * 64;
    constexpr int NELEM = NROW * 16;
    constexpr int NIT = (NELEM + NTHR - 1) / NTHR;
    __shared__ __align__(16) unsigned short sB[2 * BUFS];

    const int tid = threadIdx.x;
    const int w = tid >> 6, lane = tid & 63;
    const int tileX = blockIdx.x % tilesX, tileY = blockIdx.x / tilesX;
    const int px0 = tileX * TPX, py0 = tileY * TPY;
    const int n = blockIdx.z;
    const int mt = blockIdx.y;
    const int ocb = mt * 32;
    const int HW = H * W;
    const int ICC = C >> 4, MT = C >> 5;
    const int offx = (w % WX) * 8, offy = (w / WX) * 4;
    const int xl = lane & 7, yl = (lane >> 3) & 3;
    const int half = lane >> 5;
    const int ncbase = n * C;

    // conv2: zero the *other* ping-pong sum buffer for the next conv1
    if (CONV2 && blockIdx.x == 0 && blockIdx.z == 0) {
        int per = (2 * NCtot + MT - 1) / MT;
        int st = mt * per;
        int en = st + per; if (en > 2 * NCtot) en = 2 * NCtot;
        for (int i = st + tid; i < en; i += NTHR) sums_out[i] = 0.f;
    }

    float stg[NIT];
    auto stageLoad = [&](int icc) {
#pragma unroll
        for (int i = 0; i < NIT; i++) {
            int e = tid + i * NTHR;
            float v = 0.f;
            if (e < NELEM) {
                int ic = e / NROW; int r = e - ic * NROW;
                int yy = r / HX, xx = r - yy * HX;
                int gy = py0 + yy - 1, gx = px0 + xx - 1;
                if (gy >= 0 && gy < H && gx >= 0 && gx < W) {
                    int nc = ncbase + icc * 16 + ic;
                    v = in[(size_t)nc * HW + gy * W + gx];
                    if (CONV2) {
                        float s  = sums_in[nc];
                        float sq = sums_in[NCtot + nc];
                        float m = s * inv_hw;
                        float rst = rsqrtf(fmaf(-m, m, sq * inv_hw) + 1e-5f);
                        v = (v - m) * rst;
                    }
                }
            }
            stg[i] = v;
        }
    };
    auto stageWrite = [&](int b) {
#pragma unroll
        for (int i = 0; i < NIT; i++) {
            int e = tid + i * NTHR;
            if (e < NELEM) {
                int ic = e / NROW; int r = e - ic * NROW;
                unsigned short h = bf16_rtne(stg[i]);
                float hf = __builtin_bit_cast(float, (unsigned)h << 16);
                unsigned short lo = bf16_rtne(stg[i] - hf);
                int off = b * BUFS + r * RS + ic;
                sB[off] = h;
                sB[off + PL] = lo;
            }
        }
    };
    auto loadA = [&](int icc, int kp, s16x8& oh, s16x8& ol) {
        size_t ao = (((size_t)kp * ICC + icc) * MT + mt) * 512 + lane * 8;
        oh = *(const s16x8*)&pAhi[ao];
        ol = *(const s16x8*)&pAlo[ao];
    };
    auto loadB = [&](int b, int kp, s16x8& oh, s16x8& ol) {
        int kh = kp / 3, kw = kp - kh * 3;
        int px = (yl + offy + kh) * HX + (xl + offx + kw);
        int off = b * BUFS + px * RS + half * 8;
        oh = *(const s16x8*)&sB[off];
        ol = *(const s16x8*)&sB[off + PL];
    };

    f32x16 accA{}, accB{}, accC{};

    stageLoad(0);
    stageWrite(0);
    __syncthreads();
    s16x8 ah, al, bh, bl;
    loadA(0, 0, ah, al);
    loadB(0, 0, bh, bl);

    for (int icc = 0; icc < ICC; ++icc) {
        int b = icc & 1;
        if (icc + 1 < ICC) stageLoad(icc + 1);   // global loads overlap MFMAs
#pragma unroll
        for (int kp = 0; kp < 9; ++kp) {
            s16x8 ahn, aln, bhn, bln;
            if (kp < 8) { loadA(icc, kp + 1, ahn, aln); loadB(b, kp + 1, bhn, bln); }
            accA = __builtin_amdgcn_mfma_f32_32x32x16_bf16(ah, bh, accA, 0, 0, 0);
            accB = __builtin_amdgcn_mfma_f32_32x32x16_bf16(al, bh, accB, 0, 0, 0);
            accC = __builtin_amdgcn_mfma_f32_32x32x16_bf16(ah, bl, accC, 0, 0, 0);
            if (kp < 8) { ah = ahn; al = aln; bh = bhn; bl = bln; }
        }
        if (icc + 1 < ICC) {
            stageWrite(b ^ 1);
            __syncthreads();
            loadA(icc + 1, 0, ah, al);
            loadB(b ^ 1, 0, bh, bl);
        }
    }

    // ---- epilogue: C/D layout col=lane&31, row=(r&3)+8*(r>>2)+4*half ----
    const int col = lane & 31;
    const int gx = px0 + offx + (col & 7);
    const int gy = py0 + offy + (col >> 3);
#pragma unroll
    for (int r = 0; r < 16; r++) {
        int row = (r & 3) + 8 * (r >> 2) + 4 * half;
        int oc = ocb + row;
        size_t idx = (size_t)(ncbase + oc) * HW + (size_t)gy * W + gx;
        float v = accA[r] + accB[r] + accC[r];
        if (!CONV2) {
            v += bias[oc];
            v = fmaxf(v, 0.f);
            ydst[idx] = v;
            // fused instnorm stats: reduce 32-lane halves, atomic per (n,oc)
            float s = v, sq = v * v;
#pragma unroll
            for (int m = 1; m < 32; m <<= 1) {
                s  += __shfl_xor(s, m, 64);
                sq += __shfl_xor(sq, m, 64);
            }
            if ((lane & 31) == 0) {
                atomicAdd(&sums_out[ncbase + oc], s);
                atomicAdd(&sums_out[NCtot + ncbase + oc], sq);
            }
        } else {
            float k = -v;
            if (mode == 0)      { accb[idx] = k;        ydst[idx] = ybase[idx] + acoef * k; }
            else if (mode == 3) { ydst[idx] = ybase[idx] + dt6 * (accb[idx] + k); }
            else                { accb[idx] += 2.f * k; ydst[idx] = ybase[idx] + acoef * k; }
        }
    }
}

// ---------------- fp32 stem conv (Cin=3) -----------------------------------
#define TS  16
#define OCT 16
#define CIT 8
__global__ __launch_bounds__(256) void conv3x3_kernel(
    const float* __restrict__ in, const float* __restrict__ w,
    const float* __restrict__ bias, float* __restrict__ out,
    int N, int Cin, int Cout, int H, int W, int tilesX, int relu)
{
    __shared__ float sIn[CIT][TS + 2][TS + 2];
    __shared__ float sW[OCT][CIT][9];
    const int tid = threadIdx.x;
    const int tx = tid & (TS - 1), ty = tid >> 4;
    const int tileX = blockIdx.x % tilesX, tileY = blockIdx.x / tilesX;
    const int x0 = tileX * TS, y0 = tileY * TS;
    const int oc0 = blockIdx.y * OCT;
    const int n = blockIdx.z;
    const int HW = H * W;

    float acc[OCT];
#pragma unroll
    for (int o = 0; o < OCT; o++) acc[o] = 0.f;

    for (int ic0 = 0; ic0 < Cin; ic0 += CIT) {
        for (int idx = tid; idx < CIT * (TS + 2) * (TS + 2); idx += 256) {
            int c  = idx / ((TS + 2) * (TS + 2));
            int r  = idx % ((TS + 2) * (TS + 2));
            int iy = r / (TS + 2), ix = r % (TS + 2);
            int gy = y0 + iy - 1, gx = x0 + ix - 1;
            int ic = ic0 + c;
            float v = 0.f;
            if (ic < Cin && gy >= 0 && gy < H && gx >= 0 && gx < W)
                v = in[(size_t)(n * Cin + ic) * HW + gy * W + gx];
            sIn[c][iy][ix] = v;
        }
        for (int idx = tid; idx < OCT * CIT * 9; idx += 256) {
            int o = idx / (CIT * 9);
            int r = idx % (CIT * 9);
            int c = r / 9, k = r % 9;
            int oc = oc0 + o, ic = ic0 + c;
            sW[o][c][k] = (oc < Cout && ic < Cin)
                              ? w[((size_t)oc * Cin + ic) * 9 + k] : 0.f;
        }
        __syncthreads();
#pragma unroll
        for (int c = 0; c < CIT; c++)
#pragma unroll
            for (int kh = 0; kh < 3; kh++)
#pragma unroll
                for (int kw = 0; kw < 3; kw++) {
                    float v = sIn[c][ty + kh][tx + kw];
#pragma unroll
                    for (int o = 0; o < OCT; o++)
                        acc[o] = fmaf(v, sW[o][c][kh * 3 + kw], acc[o]);
                }
        __syncthreads();
    }

    int gy = y0 + ty, gx = x0 + tx;
    if (gy < H && gx < W) {
#pragma unroll
        for (int o = 0; o < OCT; o++) {
            int oc = oc0 + o;
            if (oc < Cout) {
                float v = acc[o] + bias[oc];
                if (relu) v = fmaxf(v, 0.f);
                out[(size_t)(n * Cout + oc) * HW + gy * W + gx] = v;
            }
        }
    }
}

// ---------------- instance-norm stats (stem/conn/head only) ----------------
__global__ __launch_bounds__(256) void stats_kernel(
    const float* __restrict__ x, float* __restrict__ mu, float* __restrict__ rstd,
    int HW, float inv_hw)
{
    int nc = blockIdx.x;
    const float* p = x + (size_t)nc * HW;
    float s = 0.f, ss = 0.f;
    for (int i = threadIdx.x; i < HW; i += 256) {
        float v = p[i];
        s += v;
        ss = fmaf(v, v, ss);
    }
    for (int off = 32; off; off >>= 1) {
        s  += __shfl_down(s, off, 64);
        ss += __shfl_down(ss, off, 64);
    }
    __shared__ float aS[4], aSS[4];
    int wid = threadIdx.x >> 6, lane = threadIdx.x & 63;
    if (lane == 0) { aS[wid] = s; aSS[wid] = ss; }
    __syncthreads();
    if (threadIdx.x == 0) {
        s  = aS[0] + aS[1] + aS[2] + aS[3];
        ss = aSS[0] + aSS[1] + aSS[2] + aSS[3];
        float m = s * inv_hw;
        float var = fmaf(-m, m, ss * inv_hw);
        mu[nc] = m;
        rstd[nc] = rsqrtf(var + 1e-5f);
    }
}

__global__ __launch_bounds__(256) void norm_affine_relu_kernel(
    const float* __restrict__ in, float* __restrict__ out,
    const float* __restrict__ mu, const float* __restrict__ rstd,
    const float* __restrict__ g, const float* __restrict__ b,
    int C, int HW, size_t total)
{
    size_t i = (size_t)blockIdx.x * 256 + threadIdx.x;
    if (i >= total) return;
    size_t nc = i / HW;
    int c = (int)(nc % C);
    float v = (in[i] - mu[nc]) * rstd[nc] * g[c] + b[c];
    out[i] = fmaxf(v, 0.f);
}

__global__ __launch_bounds__(256) void avgpool2_kernel(
    const float* __restrict__ in, float* __restrict__ out,
    int Ho, int Wo, size_t total)
{
    size_t i = (size_t)blockIdx.x * 256 + threadIdx.x;
    if (i >= total) return;
    int wo = (int)(i % Wo);
    int ho = (int)((i / Wo) % Ho);
    size_t nc = i / ((size_t)Wo * Ho);
    const float* p = in + nc * (size_t)(4 * Ho * Wo) + (size_t)(2 * ho) * (2 * Wo) + 2 * wo;
    out[i] = 0.25f * (p[0] + p[1] + p[2 * Wo] + p[2 * Wo + 1]);
}

#define C1OCT 8
__global__ __launch_bounds__(256) void conv1x1_kernel(
    const float* __restrict__ in, const float* __restrict__ w,
    const float* __restrict__ bias, float* __restrict__ out,
    int Cin, int Cout, int HW)
{
    int p = blockIdx.x * 256 + threadIdx.x;
    int oc0 = blockIdx.y * C1OCT;
    int n = blockIdx.z;
    if (p >= HW) return;
    float acc[C1OCT];
#pragma unroll
    for (int o = 0; o < C1OCT; o++) acc[o] = 0.f;
    const float* ip = in + (size_t)n * Cin * HW + p;
    for (int ic = 0; ic < Cin; ic++) {
        float v = ip[(size_t)ic * HW];
#pragma unroll
        for (int o = 0; o < C1OCT; o++)
            acc[o] = fmaf(v, w[(size_t)(oc0 + o) * Cin + ic], acc[o]);
    }
    float* op = out + ((size_t)n * Cout + oc0) * HW + p;
#pragma unroll
    for (int o = 0; o < C1OCT; o++) op[(size_t)o * HW] = acc[o] + bias[oc0 + o];
}

__global__ __launch_bounds__(128) void head_kernel(
    const float* __restrict__ m, const float* __restrict__ hw,
    const float* __restrict__ hb, float* __restrict__ out, int C)
{
    int t = threadIdx.x;
    if (t < 80) {
        int n = t / 10, k = t % 10;
        float acc = hb[k];
        for (int c = 0; c < C; c++)
            acc = fmaf(m[n * C + c], hw[k * C + c], acc);
        out[t] = acc;
    }
}

// ---------------------------------------------------------------------------
// host orchestration
// ---------------------------------------------------------------------------
struct OdeCfg { int C, H, tilesX, gridX; };
static const OdeCfg CFG[3] = {
    {64, 96, 6, 72},
    {128, 48, 3, 18},
    {256, 24, 3, 9},
};

static void launch_c1(int st, const float* in, const unsigned short* ph,
                      const float* bias, float* sums_w, float* z, hipStream_t s)
{
    const OdeCfg& c = CFG[st];
    const size_t PLANE = (size_t)36 * c.C * c.C;
    dim3 g(c.gridX, c.C / 32, 8);
    float ih = 1.f / (c.H * c.H);
    if (st == 2)
        conv_mfma2<2, 1, false><<<g, 128, 0, s>>>(in, ph, ph + PLANE, bias,
            nullptr, sums_w, nullptr, nullptr, z,
            c.C, c.H, c.H, c.tilesX, 8 * c.C, ih, 0, 0.f, 0.f);
    else
        conv_mfma2<4, 2, false><<<g, 256, 0, s>>>(in, ph, ph + PLANE, bias,
            nullptr, sums_w, nullptr, nullptr, z,
            c.C, c.H, c.H, c.tilesX, 8 * c.C, ih, 0, 0.f, 0.f);
}

static void launch_c2(int st, const float* z, const unsigned short* ph,
                      const float* sums_r, float* sums_z,
                      const float* ybase, float* accb, float* ydst,
                      int mode, float acoef, hipStream_t s)
{
    const OdeCfg& c = CFG[st];
    const size_t PLANE = (size_t)36 * c.C * c.C;
    dim3 g(c.gridX, c.C / 32, 8);
    float ih = 1.f / (c.H * c.H);
    const float dt6 = 0.25f / 6.f;
    if (st == 2)
        conv_mfma2<2, 1, true><<<g, 128, 0, s>>>(z, ph, ph + PLANE, nullptr,
            sums_r, sums_z, ybase, accb, ydst,
            c.C, c.H, c.H, c.tilesX, 8 * c.C, ih, mode, acoef, dt6);
    else
        conv_mfma2<4, 2, true><<<g, 256, 0, s>>>(z, ph, ph + PLANE, nullptr,
            sums_r, sums_z, ybase, accb, ydst,
            c.C, c.H, c.H, c.tilesX, 8 * c.C, ih, mode, acoef, dt6);
}

static void ode_block_mfma(int st, float* y, float* t, float* z, float* a,
                           float* sums, int& par, unsigned short* pack,
                           const float* bbank, hipStream_t s)
{
    const OdeCfg& c = CFG[st];
    const int C = c.C;
    const size_t PLANE = (size_t)36 * C * C;
    const size_t BANKW = (size_t)9 * C * C;
    const float dt = 0.25f;
    for (int i = 0; i < 4; i++) {
        int j = (i + 1 > 3) ? 3 : i + 1;
        const unsigned short* p1  = pack + i * BANKW;              // dir0 hi
        const unsigned short* p1t = pack + 2 * PLANE + i * BANKW;  // dir1 hi
        const unsigned short* p4  = pack + j * BANKW;
        const unsigned short* p4t = pack + 2 * PLANE + j * BANKW;
        const float* b1 = bbank + (size_t)i * C;
        const float* b4 = bbank + (size_t)j * C;

        // k1
        launch_c1(st, y, p1, b1, sums + par * 4096, z, s);
        launch_c2(st, z, p1t, sums + par * 4096, sums + (par ^ 1) * 4096,
                  y, a, t, 0, 0.5f * dt, s);
        par ^= 1;
        // k2
        launch_c1(st, t, p1, b1, sums + par * 4096, z, s);
        launch_c2(st, z, p1t, sums + par * 4096, sums + (par ^ 1) * 4096,
                  y, a, t, 1, 0.5f * dt, s);
        par ^= 1;
        // k3
        launch_c1(st, t, p1, b1, sums + par * 4096, z, s);
        launch_c2(st, z, p1t, sums + par * 4096, sums + (par ^ 1) * 4096,
                  y, a, t, 1, dt, s);
        par ^= 1;
        // k4 + update
        launch_c1(st, t, p4, b4, sums + par * 4096, z, s);
        launch_c2(st, z, p4t, sums + par * 4096, sums + (par ^ 1) * 4096,
                  y, a, y, 3, 0.f, s);
        par ^= 1;
    }
}

extern "C" void kernel_launch(void* const* d_in, const int* in_sizes, int n_in,
                              void* d_out, int out_size, void* d_ws, size_t ws_size,
                              hipStream_t stream)
{
    const float* x       = (const float*)d_in[0];
    const float* stem_w  = (const float*)d_in[1];
    const float* stem_b  = (const float*)d_in[2];
    const float* norm1_g = (const float*)d_in[3];
    const float* norm1_b = (const float*)d_in[4];
    const float* ode1_W  = (const float*)d_in[5];
    const float* ode1_b  = (const float*)d_in[6];
    const float* conn1_w = (const float*)d_in[7];
    const float* conn1_b = (const float*)d_in[8];
    const float* norm3_g = (const float*)d_in[9];
    const float* norm3_b = (const float*)d_in[10];
    const float* ode2_W  = (const float*)d_in[11];
    const float* ode2_b  = (const float*)d_in[12];
    const float* conn2_w = (const float*)d_in[13];
    const float* conn2_b = (const float*)d_in[14];
    const float* norm4_g = (const float*)d_in[15];
    const float* norm4_b = (const float*)d_in[16];
    const float* ode3_W  = (const float*)d_in[17];
    const float* ode3_b  = (const float*)d_in[18];
    const float* head_w  = (const float*)d_in[19];
    const float* head_b  = (const float*)d_in[20];
    float* out = (float*)d_out;

    float* ws = (float*)d_ws;
    const size_t BUF = 4718592; // 8*64*96*96
    float* y    = ws;
    float* t    = ws + BUF;
    float* z    = ws + 2 * BUF;
    float* a    = ws + 3 * BUF;
    float* mu   = ws + 4 * BUF;           // 2048
    float* rs   = mu + 2048;              // 2048
    float* sums = ws + 4 * BUF + 4096;    // 2 ping-pong bufs x 4096 floats
    unsigned short* pack = (unsigned short*)(ws + 4 * BUF + 4096 + 8192);

    hipMemsetAsync(sums, 0, 8192 * sizeof(float), stream);
    int par = 0;

    // ---- stem: conv3x3(3->64)+b -> IN(affine) -> relu ----
    {
        int H = 96, tiles = 6;
        dim3 grid(tiles * tiles, 64 / OCT, 8);
        conv3x3_kernel<<<grid, 256, 0, stream>>>(x, stem_w, stem_b, z,
                                                 8, 3, 64, H, H, tiles, 0);
        stats_kernel<<<8 * 64, 256, 0, stream>>>(z, mu, rs, H * H, 1.f / (H * H));
        size_t total = (size_t)8 * 64 * H * H;
        norm_affine_relu_kernel<<<(total + 255) / 256, 256, 0, stream>>>(
            z, y, mu, rs, norm1_g, norm1_b, 64, H * H, total);
    }

    // ---- ode1 ----
    {
        size_t PLANE = (size_t)36 * 64 * 64;
        pack_weights<<<dim3((PLANE + 255) / 256, 2), 256, 0, stream>>>(ode1_W, pack, 64);
        ode_block_mfma(0, y, t, z, a, sums, par, pack, ode1_b, stream);
    }

    // ---- conn1: 1x1(64->128) -> IN+relu -> pool ----
    {
        int H = 96, HW = H * H, Cin = 64, Cout = 128;
        dim3 grid((HW + 255) / 256, Cout / C1OCT, 8);
        conv1x1_kernel<<<grid, 256, 0, stream>>>(y, conn1_w, conn1_b, t, Cin, Cout, HW);
        stats_kernel<<<8 * Cout, 256, 0, stream>>>(t, mu, rs, HW, 1.f / HW);
        size_t total = (size_t)8 * Cout * HW;
        norm_affine_relu_kernel<<<(total + 255) / 256, 256, 0, stream>>>(
            t, t, mu, rs, norm3_g, norm3_b, Cout, HW, total);
        size_t ptotal = (size_t)8 * Cout * 48 * 48;
        avgpool2_kernel<<<(ptotal + 255) / 256, 256, 0, stream>>>(t, y, 48, 48, ptotal);
    }

    // ---- ode2 ----
    {
        size_t PLANE = (size_t)36 * 128 * 128;
        pack_weights<<<dim3((PLANE + 255) / 256, 2), 256, 0, stream>>>(ode2_W, pack, 128);
        ode_block_mfma(1, y, t, z, a, sums, par, pack, ode2_b, stream);
    }

    // ---- conn2: 1x1(128->256) -> IN+relu -> pool ----
    {
        int H = 48, HW = H * H, Cin = 128, Cout = 256;
        dim3 grid((HW + 255) / 256, Cout / C1OCT, 8);
        conv1x1_kernel<<<grid, 256, 0, stream>>>(y, conn2_w, conn2_b, t, Cin, Cout, HW);
        stats_kernel<<<8 * Cout, 256, 0, stream>>>(t, mu, rs, HW, 1.f / HW);
        size_t total = (size_t)8 * Cout * HW;
        norm_affine_relu_kernel<<<(total + 255) / 256, 256, 0, stream>>>(
            t, t, mu, rs, norm4_g, norm4_b, Cout, HW, total);
        size_t ptotal = (size_t)8 * Cout * 24 * 24;
        avgpool2_kernel<<<(ptotal + 255) / 256, 256, 0, stream>>>(t, y, 24, 24, ptotal);
    }

    // ---- ode3 ----
    {
        size_t PLANE = (size_t)36 * 256 * 256;
        pack_weights<<<dim3((PLANE + 255) / 256, 2), 256, 0, stream>>>(ode3_W, pack, 256);
        ode_block_mfma(2, y, t, z, a, sums, par, pack, ode3_b, stream);
    }

    // ---- head: GAP + linear ----
    {
        int H = 24, HW = H * H, C = 256;
        stats_kernel<<<8 * C, 256, 0, stream>>>(y, mu, rs, HW, 1.f / HW);
        head_kernel<<<1, 128, 0, stream>>>(mu, head_w, head_b, out, C);
    }
}

// Round 4
// 7492.216 us; speedup vs baseline: 10.2354x; 1.0793x over previous
//
#include <hip/hip_runtime.h>

// ---------------------------------------------------------------------------
// MPNODE_STL10 forward, round 4: split-bf16 MFMA conv, latency-restructured.
//  - A (weights) bulk-loaded per ic-chunk into VGPRs (9 kp x hi/lo = 72 regs,
//    repacked contiguous) -> no global ops inside the kp loop; staging loads
//    for the next B-chunk stay outstanding across all 27 MFMAs.
//  - LDS B row stride = 20 shorts (40 B) -> <=2-way bank aliasing (free) for
//    both staging ds_writes (r-fast) and fragment ds_read_b128.
//  - instnorm stats: wave shuffle-reduce -> LDS block-reduce -> ONE atomicAdd
//    pair per (block, oc): 8x less atomic contention than per-wave atomics.
//  - RK4 stage update fused in conv2 epilogue; mu/rstd inline in conv2 staging.
// ---------------------------------------------------------------------------

typedef __attribute__((ext_vector_type(8)))  short  s16x8;
typedef __attribute__((ext_vector_type(16))) float  f32x16;

__device__ __forceinline__ unsigned short bf16_rtne(float f) {
    unsigned u = __builtin_bit_cast(unsigned, f);
    unsigned r = u + 0x7FFFu + ((u >> 16) & 1u);
    return (unsigned short)(r >> 16);
}

// ---------------- weight pack ----------------------------------------------
// Per dir (0=conv, 1=transposed+flipped), per bank(4):
//   [icc(C/16)][mt(C/32)][kp(9)][pl(2: hi,lo)][lane(64)][j(8)]
// -> A for one (icc,mt) chunk is 9216 contiguous shorts (9 kp x 2 x 512).
// A element: m = lane&31 -> oc, k = (lane>>5)*8+j -> ic within chunk.
__global__ __launch_bounds__(256) void pack_weights(
    const float* __restrict__ Wb, unsigned short* __restrict__ out, int C)
{
    const int dir = blockIdx.y;
    const int MT = C >> 5, ICC = C >> 4;
    const size_t TOT = (size_t)36 * C * C;      // hi/lo pairs per dir
    size_t t = (size_t)blockIdx.x * 256 + threadIdx.x;
    if (t >= TOT) return;
    int j = t & 7;
    int l = (t >> 3) & 63;
    size_t r = t >> 9;
    int kp  = r % 9;  r /= 9;
    int mt  = r % MT; r /= MT;
    int icc = r % ICC; r /= ICC;
    int bank = (int)r;
    int oc = mt * 32 + (l & 31);
    int ic = icc * 16 + (l >> 5) * 8 + j;
    int kh = kp / 3, kw = kp % 3;
    float v;
    if (dir == 0)
        v = Wb[(((size_t)(bank * C + oc) * C + ic) * 3 + kh) * 3 + kw];
    else
        v = Wb[(((size_t)(bank * C + ic) * C + oc) * 3 + (2 - kh)) * 3 + (2 - kw)];
    unsigned short h = bf16_rtne(v);
    float hf = __builtin_bit_cast(float, (unsigned)h << 16);
    unsigned short lo = bf16_rtne(v - hf);
    size_t idx = ((((size_t)bank * ICC + icc) * MT + mt) * 9 + kp) * 1024 + l * 8 + j;
    unsigned short* base = out + (size_t)dir * 72 * C * C;
    base[idx] = h;
    base[idx + 512] = lo;
}

// ---------------- MFMA conv kernel -----------------------------------------
template<int NW, int WX, bool CONV2>
__global__ __launch_bounds__(NW * 64) void conv_mfma3(
    const float* __restrict__ in,
    const unsigned short* __restrict__ pA,   // (dir,bank) base, packed layout
    const float* __restrict__ bias,
    const float* __restrict__ sums_in,       // conv2: [s | ss], 2*NCtot floats
    float* __restrict__ sums_out,            // conv1: accumulate; conv2: zero
    const float* __restrict__ ybase, float* __restrict__ accb,
    float* __restrict__ ydst,
    int C, int H, int W, int tilesX, int NCtot, float inv_hw,
    int mode, float acoef, float dt6)
{
    constexpr int TPX = 8 * WX, TPY = 4 * (NW / WX);
    constexpr int HX = TPX + 2, HY = TPY + 2;
    constexpr int NROW = HX * HY;
    constexpr int RS = 20;               // row stride (shorts), 40B
    constexpr int PL = NROW * RS;
    constexpr int BUFS = 2 * PL;         // hi plane + lo plane
    constexpr int NTHR = NW * 64;
    constexpr int NELEM = NROW * 16;
    constexpr int NIT = (NELEM + NTHR - 1) / NTHR;
    __shared__ __align__(16) unsigned short sB[2 * BUFS];

    const int tid = threadIdx.x;
    const int w = tid >> 6, lane = tid & 63;
    const int tileX = blockIdx.x % tilesX, tileY = blockIdx.x / tilesX;
    const int px0 = tileX * TPX, py0 = tileY * TPY;
    const int n = blockIdx.z;
    const int mt = blockIdx.y;
    const int ocb = mt * 32;
    const int HW = H * W;
    const int ICC = C >> 4, MT = C >> 5;
    const int offx = (w % WX) * 8, offy = (w / WX) * 4;
    const int xl = lane & 7, yl = (lane >> 3) & 3;
    const int half = lane >> 5;
    const int ncbase = n * C;

    // conv2: zero the *other* ping-pong sum buffer for the next conv1
    if (CONV2 && blockIdx.x == 0 && blockIdx.z == 0) {
        int per = (2 * NCtot + MT - 1) / MT;
        int st = mt * per;
        int en = st + per; if (en > 2 * NCtot) en = 2 * NCtot;
        for (int i = st + tid; i < en; i += NTHR) sums_out[i] = 0.f;
    }

    float stg[NIT];
    auto stageLoad = [&](int icc) {
#pragma unroll
        for (int i = 0; i < NIT; i++) {
            int e = tid + i * NTHR;
            float v = 0.f;
            if (e < NELEM) {
                int ic = e / NROW; int r = e - ic * NROW;
                int yy = r / HX, xx = r - yy * HX;
                int gy = py0 + yy - 1, gx = px0 + xx - 1;
                if (gy >= 0 && gy < H && gx >= 0 && gx < W) {
                    int nc = ncbase + icc * 16 + ic;
                    v = in[(size_t)nc * HW + gy * W + gx];
                    if (CONV2) {
                        float s  = sums_in[nc];
                        float sq = sums_in[NCtot + nc];
                        float m = s * inv_hw;
                        float rst = rsqrtf(fmaf(-m, m, sq * inv_hw) + 1e-5f);
                        v = (v - m) * rst;
                    }
                }
            }
            stg[i] = v;
        }
    };
    auto stageWrite = [&](int b) {
#pragma unroll
        for (int i = 0; i < NIT; i++) {
            int e = tid + i * NTHR;
            if (e < NELEM) {
                int ic = e / NROW; int r = e - ic * NROW;
                unsigned short h = bf16_rtne(stg[i]);
                float hf = __builtin_bit_cast(float, (unsigned)h << 16);
                unsigned short lo = bf16_rtne(stg[i] - hf);
                int off = b * BUFS + r * RS + ic;
                sB[off] = h;
                sB[off + PL] = lo;
            }
        }
    };
    auto loadB = [&](int b, int kp, s16x8& oh, s16x8& ol) {
        int kh = kp / 3, kw = kp - kh * 3;
        int px = (yl + offy + kh) * HX + (xl + offx + kw);
        int off = b * BUFS + px * RS + half * 8;
        oh = *(const s16x8*)&sB[off];
        ol = *(const s16x8*)&sB[off + PL];
    };

    f32x16 accA{}, accB{}, accC{};

    stageLoad(0);
    stageWrite(0);
    __syncthreads();

    for (int icc = 0; icc < ICC; ++icc) {
        // ---- bulk A loads: whole chunk's 9 kp hi+lo into regs ----
        s16x8 aH[9], aL[9];
        {
            const unsigned short* ab =
                pA + ((size_t)(icc * MT + mt)) * 9216 + lane * 8;
#pragma unroll
            for (int kp = 0; kp < 9; ++kp) {
                aH[kp] = *(const s16x8*)(ab + kp * 1024);
                aL[kp] = *(const s16x8*)(ab + kp * 1024 + 512);
            }
        }
        const int b = icc & 1;
        if (icc + 1 < ICC) stageLoad(icc + 1);   // stays outstanding over MFMAs

        s16x8 bh, bl;
        loadB(b, 0, bh, bl);
#pragma unroll
        for (int kp = 0; kp < 9; ++kp) {
            s16x8 bhn, bln;
            if (kp < 8) loadB(b, kp + 1, bhn, bln);
            accA = __builtin_amdgcn_mfma_f32_32x32x16_bf16(aH[kp], bh, accA, 0, 0, 0);
            accB = __builtin_amdgcn_mfma_f32_32x32x16_bf16(aL[kp], bh, accB, 0, 0, 0);
            accC = __builtin_amdgcn_mfma_f32_32x32x16_bf16(aH[kp], bl, accC, 0, 0, 0);
            if (kp < 8) { bh = bhn; bl = bln; }
        }
        if (icc + 1 < ICC) {
            stageWrite(b ^ 1);
            __syncthreads();
        }
    }

    // ---- epilogue: C/D layout col=lane&31, row=(r&3)+8*(r>>2)+4*half ----
    const int col = lane & 31;
    const int gx = px0 + offx + (col & 7);
    const int gy = py0 + offy + (col >> 3);
    float* sred = (float*)sB;   // reuse buffer-0 region (last chunk used buf 1)
#pragma unroll
    for (int r = 0; r < 16; r++) {
        int row = (r & 3) + 8 * (r >> 2) + 4 * half;
        int oc = ocb + row;
        size_t idx = (size_t)(ncbase + oc) * HW + (size_t)gy * W + gx;
        float v = accA[r] + accB[r] + accC[r];
        if (!CONV2) {
            v += bias[oc];
            v = fmaxf(v, 0.f);
            ydst[idx] = v;
            float s = v, sq = v * v;
#pragma unroll
            for (int m = 1; m < 32; m <<= 1) {
                s  += __shfl_xor(s, m, 64);
                sq += __shfl_xor(sq, m, 64);
            }
            if ((lane & 31) == 0) {
                int slot = ((w * 2 + half) * 16 + r) * 2;
                sred[slot] = s;
                sred[slot + 1] = sq;
            }
        } else {
            float k = -v;
            if (mode == 0)      { accb[idx] = k;        ydst[idx] = ybase[idx] + acoef * k; }
            else if (mode == 3) { ydst[idx] = ybase[idx] + dt6 * (accb[idx] + k); }
            else                { accb[idx] += 2.f * k; ydst[idx] = ybase[idx] + acoef * k; }
        }
    }
    if (!CONV2) {
        __syncthreads();
        if (tid < 32) {
            // row(r,half) == tid by construction
            int h2 = (tid >> 2) & 1;
            int r  = (tid & 3) | ((tid >> 3) << 2);
            float s = 0.f, sq = 0.f;
#pragma unroll
            for (int wv = 0; wv < NW; wv++) {
                int slot = ((wv * 2 + h2) * 16 + r) * 2;
                s  += sred[slot];
                sq += sred[slot + 1];
            }
            atomicAdd(&sums_out[ncbase + ocb + tid], s);
            atomicAdd(&sums_out[NCtot + ncbase + ocb + tid], sq);
        }
    }
}

// ---------------- fp32 stem conv (Cin=3) -----------------------------------
#define TS  16
#define OCT 16
#define CIT 8
__global__ __launch_bounds__(256) void conv3x3_kernel(
    const float* __restrict__ in, const float* __restrict__ w,
    const float* __restrict__ bias, float* __restrict__ out,
    int N, int Cin, int Cout, int H, int W, int tilesX, int relu)
{
    __shared__ float sIn[CIT][TS + 2][TS + 2];
    __shared__ float sW[OCT][CIT][9];
    const int tid = threadIdx.x;
    const int tx = tid & (TS - 1), ty = tid >> 4;
    const int tileX = blockIdx.x % tilesX, tileY = blockIdx.x / tilesX;
    const int x0 = tileX * TS, y0 = tileY * TS;
    const int oc0 = blockIdx.y * OCT;
    const int n = blockIdx.z;
    const int HW = H * W;

    float acc[OCT];
#pragma unroll
    for (int o = 0; o < OCT; o++) acc[o] = 0.f;

    for (int ic0 = 0; ic0 < Cin; ic0 += CIT) {
        for (int idx = tid; idx < CIT * (TS + 2) * (TS + 2); idx += 256) {
            int c  = idx / ((TS + 2) * (TS + 2));
            int r  = idx % ((TS + 2) * (TS + 2));
            int iy = r / (TS + 2), ix = r % (TS + 2);
            int gy = y0 + iy - 1, gx = x0 + ix - 1;
            int ic = ic0 + c;
            float v = 0.f;
            if (ic < Cin && gy >= 0 && gy < H && gx >= 0 && gx < W)
                v = in[(size_t)(n * Cin + ic) * HW + gy * W + gx];
            sIn[c][iy][ix] = v;
        }
        for (int idx = tid; idx < OCT * CIT * 9; idx += 256) {
            int o = idx / (CIT * 9);
            int r = idx % (CIT * 9);
            int c = r / 9, k = r % 9;
            int oc = oc0 + o, ic = ic0 + c;
            sW[o][c][k] = (oc < Cout && ic < Cin)
                              ? w[((size_t)oc * Cin + ic) * 9 + k] : 0.f;
        }
        __syncthreads();
#pragma unroll
        for (int c = 0; c < CIT; c++)
#pragma unroll
            for (int kh = 0; kh < 3; kh++)
#pragma unroll
                for (int kw = 0; kw < 3; kw++) {
                    float v = sIn[c][ty + kh][tx + kw];
#pragma unroll
                    for (int o = 0; o < OCT; o++)
                        acc[o] = fmaf(v, sW[o][c][kh * 3 + kw], acc[o]);
                }
        __syncthreads();
    }

    int gy = y0 + ty, gx = x0 + tx;
    if (gy < H && gx < W) {
#pragma unroll
        for (int o = 0; o < OCT; o++) {
            int oc = oc0 + o;
            if (oc < Cout) {
                float v = acc[o] + bias[oc];
                if (relu) v = fmaxf(v, 0.f);
                out[(size_t)(n * Cout + oc) * HW + gy * W + gx] = v;
            }
        }
    }
}

// ---------------- instance-norm stats (stem/conn/head only) ----------------
__global__ __launch_bounds__(256) void stats_kernel(
    const float* __restrict__ x, float* __restrict__ mu, float* __restrict__ rstd,
    int HW, float inv_hw)
{
    int nc = blockIdx.x;
    const float* p = x + (size_t)nc * HW;
    float s = 0.f, ss = 0.f;
    for (int i = threadIdx.x; i < HW; i += 256) {
        float v = p[i];
        s += v;
        ss = fmaf(v, v, ss);
    }
    for (int off = 32; off; off >>= 1) {
        s  += __shfl_down(s, off, 64);
        ss += __shfl_down(ss, off, 64);
    }
    __shared__ float aS[4], aSS[4];
    int wid = threadIdx.x >> 6, lane = threadIdx.x & 63;
    if (lane == 0) { aS[wid] = s; aSS[wid] = ss; }
    __syncthreads();
    if (threadIdx.x == 0) {
        s  = aS[0] + aS[1] + aS[2] + aS[3];
        ss = aSS[0] + aSS[1] + aSS[2] + aSS[3];
        float m = s * inv_hw;
        float var = fmaf(-m, m, ss * inv_hw);
        mu[nc] = m;
        rstd[nc] = rsqrtf(var + 1e-5f);
    }
}

__global__ __launch_bounds__(256) void norm_affine_relu_kernel(
    const float* __restrict__ in, float* __restrict__ out,
    const float* __restrict__ mu, const float* __restrict__ rstd,
    const float* __restrict__ g, const float* __restrict__ b,
    int C, int HW, size_t total)
{
    size_t i = (size_t)blockIdx.x * 256 + threadIdx.x;
    if (i >= total) return;
    size_t nc = i / HW;
    int c = (int)(nc % C);
    float v = (in[i] - mu[nc]) * rstd[nc] * g[c] + b[c];
    out[i] = fmaxf(v, 0.f);
}

__global__ __launch_bounds__(256) void avgpool2_kernel(
    const float* __restrict__ in, float* __restrict__ out,
    int Ho, int Wo, size_t total)
{
    size_t i = (size_t)blockIdx.x * 256 + threadIdx.x;
    if (i >= total) return;
    int wo = (int)(i % Wo);
    int ho = (int)((i / Wo) % Ho);
    size_t nc = i / ((size_t)Wo * Ho);
    const float* p = in + nc * (size_t)(4 * Ho * Wo) + (size_t)(2 * ho) * (2 * Wo) + 2 * wo;
    out[i] = 0.25f * (p[0] + p[1] + p[2 * Wo] + p[2 * Wo + 1]);
}

#define C1OCT 8
__global__ __launch_bounds__(256) void conv1x1_kernel(
    const float* __restrict__ in, const float* __restrict__ w,
    const float* __restrict__ bias, float* __restrict__ out,
    int Cin, int Cout, int HW)
{
    int p = blockIdx.x * 256 + threadIdx.x;
    int oc0 = blockIdx.y * C1OCT;
    int n = blockIdx.z;
    if (p >= HW) return;
    float acc[C1OCT];
#pragma unroll
    for (int o = 0; o < C1OCT; o++) acc[o] = 0.f;
    const float* ip = in + (size_t)n * Cin * HW + p;
    for (int ic = 0; ic < Cin; ic++) {
        float v = ip[(size_t)ic * HW];
#pragma unroll
        for (int o = 0; o < C1OCT; o++)
            acc[o] = fmaf(v, w[(size_t)(oc0 + o) * Cin + ic], acc[o]);
    }
    float* op = out + ((size_t)n * Cout + oc0) * HW + p;
#pragma unroll
    for (int o = 0; o < C1OCT; o++) op[(size_t)o * HW] = acc[o] + bias[oc0 + o];
}

__global__ __launch_bounds__(128) void head_kernel(
    const float* __restrict__ m, const float* __restrict__ hw,
    const float* __restrict__ hb, float* __restrict__ out, int C)
{
    int t = threadIdx.x;
    if (t < 80) {
        int n = t / 10, k = t % 10;
        float acc = hb[k];
        for (int c = 0; c < C; c++)
            acc = fmaf(m[n * C + c], hw[k * C + c], acc);
        out[t] = acc;
    }
}

// ---------------------------------------------------------------------------
// host orchestration
// ---------------------------------------------------------------------------
struct OdeCfg { int C, H, tilesX, gridX; };
static const OdeCfg CFG[3] = {
    {64, 96, 6, 72},
    {128, 48, 3, 18},
    {256, 24, 3, 9},
};

static void launch_c1(int st, const float* in, const unsigned short* pA,
                      const float* bias, float* sums_w, float* z, hipStream_t s)
{
    const OdeCfg& c = CFG[st];
    dim3 g(c.gridX, c.C / 32, 8);
    float ih = 1.f / (c.H * c.H);
    if (st == 2)
        conv_mfma3<2, 1, false><<<g, 128, 0, s>>>(in, pA, bias,
            nullptr, sums_w, nullptr, nullptr, z,
            c.C, c.H, c.H, c.tilesX, 8 * c.C, ih, 0, 0.f, 0.f);
    else
        conv_mfma3<4, 2, false><<<g, 256, 0, s>>>(in, pA, bias,
            nullptr, sums_w, nullptr, nullptr, z,
            c.C, c.H, c.H, c.tilesX, 8 * c.C, ih, 0, 0.f, 0.f);
}

static void launch_c2(int st, const float* z, const unsigned short* pA,
                      const float* sums_r, float* sums_z,
                      const float* ybase, float* accb, float* ydst,
                      int mode, float acoef, hipStream_t s)
{
    const OdeCfg& c = CFG[st];
    dim3 g(c.gridX, c.C / 32, 8);
    float ih = 1.f / (c.H * c.H);
    const float dt6 = 0.25f / 6.f;
    if (st == 2)
        conv_mfma3<2, 1, true><<<g, 128, 0, s>>>(z, pA, nullptr,
            sums_r, sums_z, ybase, accb, ydst,
            c.C, c.H, c.H, c.tilesX, 8 * c.C, ih, mode, acoef, dt6);
    else
        conv_mfma3<4, 2, true><<<g, 256, 0, s>>>(z, pA, nullptr,
            sums_r, sums_z, ybase, accb, ydst,
            c.C, c.H, c.H, c.tilesX, 8 * c.C, ih, mode, acoef, dt6);
}

static void ode_block_mfma(int st, float* y, float* t, float* z, float* a,
                           float* sums, int& par, unsigned short* pack,
                           const float* bbank, hipStream_t s)
{
    const OdeCfg& c = CFG[st];
    const int C = c.C;
    const size_t BANKW = (size_t)18 * C * C;   // one bank, one dir
    const size_t DIRW  = (size_t)72 * C * C;   // 4 banks
    const float dt = 0.25f;
    for (int i = 0; i < 4; i++) {
        int j = (i + 1 > 3) ? 3 : i + 1;
        const unsigned short* p1  = pack + i * BANKW;         // dir0, bank i
        const unsigned short* p1t = pack + DIRW + i * BANKW;  // dir1, bank i
        const unsigned short* p4  = pack + j * BANKW;
        const unsigned short* p4t = pack + DIRW + j * BANKW;
        const float* b1 = bbank + (size_t)i * C;
        const float* b4 = bbank + (size_t)j * C;

        launch_c1(st, y, p1, b1, sums + par * 4096, z, s);
        launch_c2(st, z, p1t, sums + par * 4096, sums + (par ^ 1) * 4096,
                  y, a, t, 0, 0.5f * dt, s);
        par ^= 1;
        launch_c1(st, t, p1, b1, sums + par * 4096, z, s);
        launch_c2(st, z, p1t, sums + par * 4096, sums + (par ^ 1) * 4096,
                  y, a, t, 1, 0.5f * dt, s);
        par ^= 1;
        launch_c1(st, t, p1, b1, sums + par * 4096, z, s);
        launch_c2(st, z, p1t, sums + par * 4096, sums + (par ^ 1) * 4096,
                  y, a, t, 1, dt, s);
        par ^= 1;
        launch_c1(st, t, p4, b4, sums + par * 4096, z, s);
        launch_c2(st, z, p4t, sums + par * 4096, sums + (par ^ 1) * 4096,
                  y, a, y, 3, 0.f, s);
        par ^= 1;
    }
}

extern "C" void kernel_launch(void* const* d_in, const int* in_sizes, int n_in,
                              void* d_out, int out_size, void* d_ws, size_t ws_size,
                              hipStream_t stream)
{
    const float* x       = (const float*)d_in[0];
    const float* stem_w  = (const float*)d_in[1];
    const float* stem_b  = (const float*)d_in[2];
    const float* norm1_g = (const float*)d_in[3];
    const float* norm1_b = (const float*)d_in[4];
    const float* ode1_W  = (const float*)d_in[5];
    const float* ode1_b  = (const float*)d_in[6];
    const float* conn1_w = (const float*)d_in[7];
    const float* conn1_b = (const float*)d_in[8];
    const float* norm3_g = (const float*)d_in[9];
    const float* norm3_b = (const float*)d_in[10];
    const float* ode2_W  = (const float*)d_in[11];
    const float* ode2_b  = (const float*)d_in[12];
    const float* conn2_w = (const float*)d_in[13];
    const float* conn2_b = (const float*)d_in[14];
    const float* norm4_g = (const float*)d_in[15];
    const float* norm4_b = (const float*)d_in[16];
    const float* ode3_W  = (const float*)d_in[17];
    const float* ode3_b  = (const float*)d_in[18];
    const float* head_w  = (const float*)d_in[19];
    const float* head_b  = (const float*)d_in[20];
    float* out = (float*)d_out;

    float* ws = (float*)d_ws;
    const size_t BUF = 4718592; // 8*64*96*96
    float* y    = ws;
    float* t    = ws + BUF;
    float* z    = ws + 2 * BUF;
    float* a    = ws + 3 * BUF;
    float* mu   = ws + 4 * BUF;           // 2048
    float* rs   = mu + 2048;              // 2048
    float* sums = ws + 4 * BUF + 4096;    // 2 ping-pong bufs x 4096 floats
    unsigned short* pack = (unsigned short*)(ws + 4 * BUF + 4096 + 8192);

    hipMemsetAsync(sums, 0, 8192 * sizeof(float), stream);
    int par = 0;

    // ---- stem: conv3x3(3->64)+b -> IN(affine) -> relu ----
    {
        int H = 96, tiles = 6;
        dim3 grid(tiles * tiles, 64 / OCT, 8);
        conv3x3_kernel<<<grid, 256, 0, stream>>>(x, stem_w, stem_b, z,
                                                 8, 3, 64, H, H, tiles, 0);
        stats_kernel<<<8 * 64, 256, 0, stream>>>(z, mu, rs, H * H, 1.f / (H * H));
        size_t total = (size_t)8 * 64 * H * H;
        norm_affine_relu_kernel<<<(total + 255) / 256, 256, 0, stream>>>(
            z, y, mu, rs, norm1_g, norm1_b, 64, H * H, total);
    }

    // ---- ode1 ----
    {
        size_t TOT = (size_t)36 * 64 * 64;
        pack_weights<<<dim3((TOT + 255) / 256, 2), 256, 0, stream>>>(ode1_W, pack, 64);
        ode_block_mfma(0, y, t, z, a, sums, par, pack, ode1_b, stream);
    }

    // ---- conn1: 1x1(64->128) -> IN+relu -> pool ----
    {
        int H = 96, HW = H * H, Cin = 64, Cout = 128;
        dim3 grid((HW + 255) / 256, Cout / C1OCT, 8);
        conv1x1_kernel<<<grid, 256, 0, stream>>>(y, conn1_w, conn1_b, t, Cin, Cout, HW);
        stats_kernel<<<8 * Cout, 256, 0, stream>>>(t, mu, rs, HW, 1.f / HW);
        size_t total = (size_t)8 * Cout * HW;
        norm_affine_relu_kernel<<<(total + 255) / 256, 256, 0, stream>>>(
            t, t, mu, rs, norm3_g, norm3_b, Cout, HW, total);
        size_t ptotal = (size_t)8 * Cout * 48 * 48;
        avgpool2_kernel<<<(ptotal + 255) / 256, 256, 0, stream>>>(t, y, 48, 48, ptotal);
    }

    // ---- ode2 ----
    {
        size_t TOT = (size_t)36 * 128 * 128;
        pack_weights<<<dim3((TOT + 255) / 256, 2), 256, 0, stream>>>(ode2_W, pack, 128);
        ode_block_mfma(1, y, t, z, a, sums, par, pack, ode2_b, stream);
    }

    // ---- conn2: 1x1(128->256) -> IN+relu -> pool ----
    {
        int H = 48, HW = H * H, Cin = 128, Cout = 256;
        dim3 grid((HW + 255) / 256, Cout / C1OCT, 8);
        conv1x1_kernel<<<grid, 256, 0, stream>>>(y, conn2_w, conn2_b, t, Cin, Cout, HW);
        stats_kernel<<<8 * Cout, 256, 0, stream>>>(t, mu, rs, HW, 1.f / HW);
        size_t total = (size_t)8 * Cout * HW;
        norm_affine_relu_kernel<<<(total + 255) / 256, 256, 0, stream>>>(
            t, t, mu, rs, norm4_g, norm4_b, Cout, HW, total);
        size_t ptotal = (size_t)8 * Cout * 24 * 24;
        avgpool2_kernel<<<(ptotal + 255) / 256, 256, 0, stream>>>(t, y, 24, 24, ptotal);
    }

    // ---- ode3 ----
    {
        size_t TOT = (size_t)36 * 256 * 256;
        pack_weights<<<dim3((TOT + 255) / 256, 2), 256, 0, stream>>>(ode3_W, pack, 256);
        ode_block_mfma(2, y, t, z, a, sums, par, pack, ode3_b, stream);
    }

    // ---- head: GAP + linear ----
    {
        int H = 24, HW = H * H, C = 256;
        stats_kernel<<<8 * C, 256, 0, stream>>>(y, mu, rs, HW, 1.f / HW);
        head_kernel<<<1, 128, 0, stream>>>(mu, head_w, head_b, out, C);
    }
}